// Round 9
// baseline (495.651 us; speedup 1.0000x reference)
//
#include <hip/hip_runtime.h>
#include <stdint.h>

// ---------------------------------------------------------------------------
// Fused 2-layer tanh RNN + FC head for MI355X (gfx950).  Round 9.
//
// = Round 8 structure with the P-pipeline off-by-one FIXED:
//   P(t) = Wih2 h1(t) + b2 = Wih2 out1[t-1] + b2  (one extra lag vs r7).
//   l2 now: skip s<2; z(s) = tanh(P(s-1) + Whh2 z(s-1-ish)) = h2_ref(s-2),
//   h2 buffers BOTH zeroed (true h2_ref(-1)=0), and TWO drain steps:
//   drain-A -> h2_ref(1022) (l1 concurrently computes P(1024)),
//   drain-B -> h2_ref(1023) -> FC.  Barriers balanced (1026/1026).
//
// KERNEL 1 xw_pre: xw[b][t] = Wih1 x[b][t] + b_ih1 + b_hh1 (fp16, MFMA C/D
//   fragment layout), 256 blocks, ~30us.
// KERNEL 2 rnn_rec: 32 blocks x 512 thr (8 waves).  Waves 0-3: layer-1
//   (32 ch each) + P = Wih2 h1 + b2 (reuses b1 frags).  Waves 4-7: layer-2
//   tail (P-read + 2 MFMA + tanh).  ONE lgkm-only barrier per step.
// LDS: canonical lane-linear fragment layout [k-block(1KB)][lane*16] ->
//   ds_read_b128 at base+lane*16 (m134/m136 conflict-free); writes <=2-way.
// ---------------------------------------------------------------------------

typedef _Float16 f16x8 __attribute__((ext_vector_type(8)));
typedef _Float16 f16x4 __attribute__((ext_vector_type(4)));
typedef float f32x4 __attribute__((ext_vector_type(4)));

#define MFMA_F16(A, B, C) __builtin_amdgcn_mfma_f32_16x16x32_f16((A), (B), (C), 0, 0, 0)

__device__ __forceinline__ float tanh_fast(float x) {
  float t = __builtin_amdgcn_exp2f(x * 2.88539008177792681472f);
  return 1.0f - 2.0f * __builtin_amdgcn_rcpf(t + 1.0f);
}

__device__ __forceinline__ uint32_t pk16(float a, float b) {
  return __builtin_bit_cast(uint32_t, __builtin_amdgcn_cvt_pkrtz(a, b));
}

__device__ __forceinline__ void sync_lds() {
  asm volatile("s_waitcnt lgkmcnt(0)\n\ts_barrier" ::: "memory");
}

__device__ __forceinline__ f16x8 cvt8w(const float* s) {
  f32x4 a = *(const f32x4*)s;
  f32x4 b = *(const f32x4*)(s + 4);
  f16x8 r;
#pragma unroll
  for (int j = 0; j < 4; ++j) { r[j] = (_Float16)a[j]; r[4 + j] = (_Float16)b[j]; }
  return r;
}

__device__ __forceinline__ f16x8 pack_x8(const f32x4& a, const f32x4& b) {
  union { uint32_t u[4]; f16x8 v; } tmp;
  tmp.u[0] = pk16(a[0], a[1]); tmp.u[1] = pk16(a[2], a[3]);
  tmp.u[2] = pk16(b[0], b[1]); tmp.u[3] = pk16(b[2], b[3]);
  return tmp.v;
}

// ============================ kernel 1: xw precompute ========================
__global__ __launch_bounds__(256) void xw_pre(
    const float* __restrict__ x, const float* __restrict__ Wih1,
    const float* __restrict__ bih1, const float* __restrict__ bhh1,
    uint2* __restrict__ xw)
{
  const int tid  = threadIdx.x;
  const int w    = tid >> 6, lane = tid & 63;
  const int g    = lane >> 4, n = lane & 15;
  const int gb   = blockIdx.x >> 3;
  const int t0   = ((blockIdx.x & 7) << 7) + (w << 5);

  f16x8 aI[8];
  f32x4 bias[8];
#pragma unroll
  for (int m = 0; m < 8; ++m) {
    aI[m] = cvt8w(Wih1 + (m * 16 + n) * 32 + g * 8);
#pragma unroll
    for (int r = 0; r < 4; ++r)
      bias[m][r] = bih1[m * 16 + g * 4 + r] + bhh1[m * 16 + g * 4 + r];
  }

  const float* xp = x + ((size_t)(gb * 16 + n) * 1024 + t0) * 32 + g * 8;
  uint2* xo = xw + (size_t)(gb * 1024 + t0) * 512 + lane;

  f32x4 xa = *(const f32x4*)(xp);
  f32x4 xb = *(const f32x4*)(xp + 4);
  for (int tt = 0; tt < 32; ++tt) {
    f32x4 na, nb;
    if (tt < 31) {
      na = *(const f32x4*)(xp + (tt + 1) * 32);
      nb = *(const f32x4*)(xp + (tt + 1) * 32 + 4);
    }
    f16x8 xf = pack_x8(xa, xb);
#pragma unroll
    for (int m = 0; m < 8; ++m) {
      f32x4 d = MFMA_F16(aI[m], xf, bias[m]);
      xo[tt * 512 + m * 64] = make_uint2(pk16(d[0], d[1]), pk16(d[2], d[3]));
    }
    xa = na; xb = nb;
  }
}

// ============================ kernel 2: recurrence ===========================
__global__ __attribute__((amdgpu_waves_per_eu(2, 2))) __launch_bounds__(512)
void rnn_rec(
    const float* __restrict__ Whh1,
    const float* __restrict__ Wih2, const float* __restrict__ Whh2,
    const float* __restrict__ bih2, const float* __restrict__ bhh2,
    const float* __restrict__ Wfc,  const float* __restrict__ bfc,
    const uint2* __restrict__ xw,
    float* __restrict__ out)
{
  constexpr int T = 1024, H1 = 128, H2 = 64, BB = 16;
  // LDS map: all fragment storage lane-linear [k-block(1KB)][lane*16].
  constexpr int H1_0 = 0,     H1_1 = 4096;   // h1: 4 k-blocks x 1KB
  constexpr int H2_0 = 8192,  H2_1 = 10240;  // h2: 2 k-blocks x 1KB
  constexpr int PB_0 = 12288, PB_1 = 16384;  // P:  4 tiles x 1KB (f32x4/lane)
  constexpr int H2F  = 20480;                // final h2 f32: 16 rows x 256B
  __shared__ __align__(16) unsigned char smem[24576];

  const int tid  = threadIdx.x;
  const int w    = tid >> 6;      // wave 0..7
  const int lane = tid & 63;
  const int g    = lane >> 4;     // 0..3
  const int n    = lane & 15;     // batch col
  const int b0   = blockIdx.x * BB;

  // zero h1 buf0 (h1(0)=0) and BOTH h2 buffers (h2_ref(-1)=0 seen at s=2)
  {
    uint32_t* p = (uint32_t*)smem;
    for (int i = tid; i < 1024; i += 512) p[i] = 0u;           // H1_0
    uint32_t* q = (uint32_t*)(smem + H2_0);
    for (int i = tid; i < 1024; i += 512) q[i] = 0u;           // H2_0 + H2_1
  }

  auto tanh_pack = [&](const f32x4& a, uint32_t& lo, uint32_t& hi) {
    lo = pk16(tanh_fast(a[0]), tanh_fast(a[1]));
    hi = pk16(tanh_fast(a[2]), tanh_fast(a[3]));
  };

  __syncthreads();

  const f32x4 zero = {0.f, 0.f, 0.f, 0.f};
  const int lb = lane * 16;  // lane-linear byte offset

  if (w < 4) {
    // ===== layer-1 wave: tiles {2w,2w+1} (ch 32w..32w+31) + P tile w =====
    f16x8 aU[2][4], aI2[4];
    f32x4 bias2v;
#pragma unroll
    for (int ti = 0; ti < 2; ++ti) {
      const int ch = (2 * w + ti) * 16 + n;
#pragma unroll
      for (int k4 = 0; k4 < 4; ++k4)
        aU[ti][k4] = cvt8w(Whh1 + ch * H1 + k4 * 32 + g * 8);
    }
#pragma unroll
    for (int k4 = 0; k4 < 4; ++k4)
      aI2[k4] = cvt8w(Wih2 + (16 * w + n) * H1 + k4 * 32 + g * 8);
#pragma unroll
    for (int r = 0; r < 4; ++r)
      bias2v[r] = bih2[16 * w + g * 4 + r] + bhh2[16 * w + g * 4 + r];

    // h1 write offsets: channel c0 = 32w+16ti+4g -> k4-block w,
    // sub-block (2ti+(g>>1)), byte n*16 + (g&1)*8
    int woff[2];
#pragma unroll
    for (int ti = 0; ti < 2; ++ti)
      woff[ti] = w * 1024 + (2 * ti + (g >> 1)) * 256 + n * 16 + (g & 1) * 8;
    const int pw_rel = w * 1024 + lb;  // P write (f32x4, lane-linear)

    const uint2* xwp = xw + (size_t)blockIdx.x * T * 512 + lane;
    const int ti0 = (2 * w) * 64, ti1 = (2 * w + 1) * 64;

    auto cvtC = [](uint2 v) -> f32x4 {
      f16x4 h = __builtin_bit_cast(f16x4, v);
      f32x4 r;
#pragma unroll
      for (int i = 0; i < 4; ++i) r[i] = (float)h[i];
      return r;
    };

    uint2 qA0 = xwp[0 * 512 + ti0], qA1 = xwp[0 * 512 + ti1];
    uint2 qB0 = xwp[1 * 512 + ti0], qB1 = xwp[1 * 512 + ti1];

    auto stepL1 = [&](int t, int cur, uint2& s0, uint2& s1) {
      const char* H1c = (const char*)smem + (cur ? H1_1 : H1_0);
      char*       H1n = (char*)smem + (cur ? H1_0 : H1_1);
      char*       Pw  = (char*)smem + (cur ? PB_1 : PB_0);
      f16x8 b1k0 = *(const f16x8*)(H1c + 0 * 1024 + lb);
      f16x8 b1k1 = *(const f16x8*)(H1c + 1 * 1024 + lb);
      f16x8 b1k2 = *(const f16x8*)(H1c + 2 * 1024 + lb);
      f16x8 b1k3 = *(const f16x8*)(H1c + 3 * 1024 + lb);
      f32x4 accI0 = cvtC(s0), accI1 = cvtC(s1);
      if (t + 2 < T) {
        s0 = xwp[(t + 2) * 512 + ti0];
        s1 = xwp[(t + 2) * 512 + ti1];
      }
      // l1 recurrence: two 2-deep chains per tile
      f32x4 aA0 = MFMA_F16(aU[0][0], b1k0, accI0);
      f32x4 aB0 = MFMA_F16(aU[0][2], b1k2, zero);
      f32x4 aA1 = MFMA_F16(aU[1][0], b1k0, accI1);
      f32x4 aB1 = MFMA_F16(aU[1][2], b1k2, zero);
      aA0 = MFMA_F16(aU[0][1], b1k1, aA0);
      aB0 = MFMA_F16(aU[0][3], b1k3, aB0);
      aA1 = MFMA_F16(aU[1][1], b1k1, aA1);
      aB1 = MFMA_F16(aU[1][3], b1k3, aB1);
      // P(t) = bias2 + Wih2 * h1(t)   (consumed by l2 at step t+1)
      {
        f32x4 cA = MFMA_F16(aI2[0], b1k0, bias2v);
        f32x4 cB = MFMA_F16(aI2[1], b1k1, zero);
        cA = MFMA_F16(aI2[2], b1k2, cA);
        cB = MFMA_F16(aI2[3], b1k3, cB);
        *(f32x4*)(Pw + pw_rel) = cA + cB;
      }
      // h1(t+1) = tanh(...)
      {
        f32x4 s0v = aA0 + aB0;
        uint32_t lo, hi;
        tanh_pack(s0v, lo, hi);
        *(uint2*)(H1n + woff[0]) = make_uint2(lo, hi);
      }
      {
        f32x4 s1v = aA1 + aB1;
        uint32_t lo, hi;
        tanh_pack(s1v, lo, hi);
        *(uint2*)(H1n + woff[1]) = make_uint2(lo, hi);
      }
      sync_lds();
    };

    for (int t = 0; t < T; t += 2) {
      stepL1(t + 0, 0, qA0, qA1);
      stepL1(t + 1, 1, qB0, qB1);
    }
    // P-drain (interval 1025): P(1024) = bias2 + Wih2 h1(1024) [H1_0] -> PB_0
    {
      const char* H1c = (const char*)smem + H1_0;
      f16x8 b1k0 = *(const f16x8*)(H1c + 0 * 1024 + lb);
      f16x8 b1k1 = *(const f16x8*)(H1c + 1 * 1024 + lb);
      f16x8 b1k2 = *(const f16x8*)(H1c + 2 * 1024 + lb);
      f16x8 b1k3 = *(const f16x8*)(H1c + 3 * 1024 + lb);
      f32x4 cA = MFMA_F16(aI2[0], b1k0, bias2v);
      f32x4 cB = MFMA_F16(aI2[1], b1k1, zero);
      cA = MFMA_F16(aI2[2], b1k2, cA);
      cB = MFMA_F16(aI2[3], b1k3, cB);
      *(f32x4*)((char*)smem + PB_0 + pw_rel) = cA + cB;
    }
    sync_lds();  // #1025 (pairs with l2 drain-A)
    sync_lds();  // #1026 (pairs with l2 drain-B)
  } else {
    // ===== layer-2 wave: tile j2 = w-4 (ch 16j2..16j2+15) =====
    const int j2 = w - 4;
    f16x8 aR2[2];
#pragma unroll
    for (int k2 = 0; k2 < 2; ++k2)
      aR2[k2] = cvt8w(Whh2 + (16 * j2 + n) * H2 + k2 * 32 + g * 8);

    const int h2w = (j2 >> 1) * 1024 + (2 * (j2 & 1) + (g >> 1)) * 256
                  + n * 16 + (g & 1) * 8;
    const int proff = j2 * 1024 + lb;

    // step s (s>=2): z(s) = tanh(P(s-1) + Whh2 * z(s-1)) = h2_ref(s-2).
    // reads P(s-1) [PB cur^1], h2 [H2 cur]; writes h2 [H2 cur^1].
    auto stepL2 = [&](int s, int cur) {
      if (s > 1) {
        const char* Pr  = (const char*)smem + (cur ? PB_0 : PB_1);
        const char* H2r = (const char*)smem + (cur ? H2_1 : H2_0);
        char*       H2w = (char*)smem + (cur ? H2_0 : H2_1);
        f32x4 part = *(const f32x4*)(Pr + proff);
        f16x8 b2k0 = *(const f16x8*)(H2r + 0 * 1024 + lb);
        f16x8 b2k1 = *(const f16x8*)(H2r + 1 * 1024 + lb);
        f32x4 z2 = MFMA_F16(aR2[0], b2k0, part);
        z2 = MFMA_F16(aR2[1], b2k1, z2);
        uint32_t lo, hi;
        tanh_pack(z2, lo, hi);
        *(uint2*)(H2w + h2w) = make_uint2(lo, hi);
      }
      sync_lds();
    };

    for (int s = 0; s < T; s += 2) {
      stepL2(s + 0, 0);
      stepL2(s + 1, 1);
    }
    // drain A (s=1024, cur=0): h2_ref(1022) = tanh(P(1023) + Whh2 h2_ref(1021))
    //   P(1023) in PB_1; h2_ref(1021) in H2_0; write -> H2_1.
    {
      const char* Pr  = (const char*)smem + PB_1;
      const char* H2r = (const char*)smem + H2_0;
      char*       H2w = (char*)smem + H2_1;
      f32x4 part = *(const f32x4*)(Pr + proff);
      f16x8 b2k0 = *(const f16x8*)(H2r + 0 * 1024 + lb);
      f16x8 b2k1 = *(const f16x8*)(H2r + 1 * 1024 + lb);
      f32x4 z2 = MFMA_F16(aR2[0], b2k0, part);
      z2 = MFMA_F16(aR2[1], b2k1, z2);
      uint32_t lo, hi;
      tanh_pack(z2, lo, hi);
      *(uint2*)(H2w + h2w) = make_uint2(lo, hi);
    }
    sync_lds();  // #1025
    // drain B (s=1025): h2_ref(1023) = tanh(P(1024) + Whh2 h2_ref(1022))
    //   P(1024) in PB_0; h2_ref(1022) in H2_1; -> f32 H2F for the FC head.
    {
      const char* Pr  = (const char*)smem + PB_0;
      const char* H2r = (const char*)smem + H2_1;
      f32x4 part = *(const f32x4*)(Pr + proff);
      f16x8 b2k0 = *(const f16x8*)(H2r + 0 * 1024 + lb);
      f16x8 b2k1 = *(const f16x8*)(H2r + 1 * 1024 + lb);
      f32x4 z2 = MFMA_F16(aR2[0], b2k0, part);
      z2 = MFMA_F16(aR2[1], b2k1, z2);
      f32x4 hv;
#pragma unroll
      for (int r = 0; r < 4; ++r) hv[r] = tanh_fast(z2[r]);
      *(f32x4*)(smem + H2F + n * 256 + (16 * j2 + 4 * g) * 4) = hv;
    }
    sync_lds();  // #1026
  }

  // ---- FC head ----
  if (tid < BB * 10) {
    const int b = tid / 10, c = tid % 10;
    const float* hrow = (const float*)(smem + H2F + b * 256);
    float acc = bfc[c];
#pragma unroll 8
    for (int k = 0; k < 64; ++k) acc += hrow[k] * Wfc[c * 64 + k];
    out[(size_t)(b0 + b) * 10 + c] = acc;
  }
}

// ============================ fallback (no ws): r4-style =====================
__global__ __launch_bounds__(512) void rnn_fallback(
    const float* __restrict__ x,
    const float* __restrict__ Wih1, const float* __restrict__ Whh1,
    const float* __restrict__ bih1, const float* __restrict__ bhh1,
    const float* __restrict__ Wih2, const float* __restrict__ Whh2,
    const float* __restrict__ bih2, const float* __restrict__ bhh2,
    const float* __restrict__ Wfc,  const float* __restrict__ bfc,
    float* __restrict__ out)
{
  constexpr int T = 1024, I = 32, H1 = 128, H2 = 64, BB = 16;
  constexpr int R1 = 272, R2 = 144;
  constexpr int H1_0 = 0, H1_1 = 4352;
  constexpr int H2_0 = 8704, H2_1 = 11008;
  constexpr int H2F  = 13312;
  __shared__ __align__(16) unsigned char smem[17408];
  const int tid = threadIdx.x, w = tid >> 6, lane = tid & 63;
  const int g = lane >> 4, n = lane & 15, b0 = blockIdx.x * BB;
  {
    uint32_t* p = (uint32_t*)smem;
    for (int i = tid; i < 1088; i += 512) p[i] = 0u;
    uint32_t* q = (uint32_t*)(smem + H2_0);
    for (int i = tid; i < 576; i += 512) q[i] = 0u;
  }
  int roff1[4];
#pragma unroll
  for (int k4 = 0; k4 < 4; ++k4) roff1[k4] = n * R1 + k4 * 64 + g * 16;
  auto tanh_pack = [&](const f32x4& a, uint32_t& lo, uint32_t& hi) {
    lo = pk16(tanh_fast(a[0]), tanh_fast(a[1]));
    hi = pk16(tanh_fast(a[2]), tanh_fast(a[3]));
  };
  __syncthreads();
  const f32x4 zero = {0.f, 0.f, 0.f, 0.f};
  if (w < 4) {
    f16x8 aU[2][4], aI1[2];
    f32x4 bias1[2];
#pragma unroll
    for (int ti = 0; ti < 2; ++ti) {
      const int ch = (2 * w + ti) * 16 + n;
#pragma unroll
      for (int k4 = 0; k4 < 4; ++k4)
        aU[ti][k4] = cvt8w(Whh1 + ch * H1 + k4 * 32 + g * 8);
      aI1[ti] = cvt8w(Wih1 + ch * I + g * 8);
      const int cb = (2 * w + ti) * 16 + g * 4;
#pragma unroll
      for (int r = 0; r < 4; ++r) bias1[ti][r] = bih1[cb + r] + bhh1[cb + r];
    }
    int woff[2];
#pragma unroll
    for (int ti = 0; ti < 2; ++ti)
      woff[ti] = n * R1 + (2 * w + ti) * 32 + g * 8;
    const float* xp = x + (size_t)(b0 + n) * T * I + g * 8;
    f32x4 qa = *(const f32x4*)(xp), qb = *(const f32x4*)(xp + 4);
    f32x4 accI0, accI1;
    {
      f16x8 xf = pack_x8(qa, qb);
      accI0 = MFMA_F16(aI1[0], xf, bias1[0]);
      accI1 = MFMA_F16(aI1[1], xf, bias1[1]);
    }
    for (int t = 0; t < T; ++t) {
      const int cur = t & 1;
      const char* H1c = (const char*)smem + (cur ? H1_1 : H1_0);
      char*       H1n = (char*)smem + (cur ? H1_0 : H1_1);
      f16x8 b1k0 = *(const f16x8*)(H1c + roff1[0]);
      f16x8 b1k1 = *(const f16x8*)(H1c + roff1[1]);
      f16x8 b1k2 = *(const f16x8*)(H1c + roff1[2]);
      f16x8 b1k3 = *(const f16x8*)(H1c + roff1[3]);
      if (t + 1 < T) {
        qa = *(const f32x4*)(xp + (t + 1) * I);
        qb = *(const f32x4*)(xp + (t + 1) * I + 4);
      }
      f32x4 aA0 = MFMA_F16(aU[0][0], b1k0, accI0);
      f32x4 aB0 = MFMA_F16(aU[0][2], b1k2, zero);
      f32x4 aA1 = MFMA_F16(aU[1][0], b1k0, accI1);
      f32x4 aB1 = MFMA_F16(aU[1][2], b1k2, zero);
      aA0 = MFMA_F16(aU[0][1], b1k1, aA0);
      aB0 = MFMA_F16(aU[0][3], b1k3, aB0);
      aA1 = MFMA_F16(aU[1][1], b1k1, aA1);
      aB1 = MFMA_F16(aU[1][3], b1k3, aB1);
      if (t + 1 < T) {
        f16x8 xf = pack_x8(qa, qb);
        accI0 = MFMA_F16(aI1[0], xf, bias1[0]);
        accI1 = MFMA_F16(aI1[1], xf, bias1[1]);
      }
      uint32_t lo, hi;
      f32x4 s0 = aA0 + aB0;
      tanh_pack(s0, lo, hi);
      *(uint2*)(H1n + woff[0]) = make_uint2(lo, hi);
      f32x4 s1 = aA1 + aB1;
      tanh_pack(s1, lo, hi);
      *(uint2*)(H1n + woff[1]) = make_uint2(lo, hi);
      sync_lds();
    }
  } else {
    const int j = w - 4;
    f16x8 aI2[4], aR2[2];
#pragma unroll
    for (int k4 = 0; k4 < 4; ++k4)
      aI2[k4] = cvt8w(Wih2 + (16 * j + n) * H1 + k4 * 32 + g * 8);
#pragma unroll
    for (int k2 = 0; k2 < 2; ++k2)
      aR2[k2] = cvt8w(Whh2 + (16 * j + n) * H2 + k2 * 32 + g * 8);
    f32x4 bias2;
#pragma unroll
    for (int r = 0; r < 4; ++r)
      bias2[r] = bih2[16 * j + g * 4 + r] + bhh2[16 * j + g * 4 + r];
    int roff2[2];
#pragma unroll
    for (int k2 = 0; k2 < 2; ++k2) roff2[k2] = n * R2 + k2 * 64 + g * 16;
    const int woff2 = n * R2 + j * 32 + g * 8;
    auto l2_body = [&](const char* H1c, const char* H2r, f32x4& s) {
      f16x8 b1k0 = *(const f16x8*)(H1c + roff1[0]);
      f16x8 b1k1 = *(const f16x8*)(H1c + roff1[1]);
      f16x8 b1k2 = *(const f16x8*)(H1c + roff1[2]);
      f16x8 b1k3 = *(const f16x8*)(H1c + roff1[3]);
      f16x8 b2k0 = *(const f16x8*)(H2r + roff2[0]);
      f16x8 b2k1 = *(const f16x8*)(H2r + roff2[1]);
      f32x4 cA = MFMA_F16(aI2[0], b1k0, bias2);
      f32x4 cB = MFMA_F16(aI2[1], b1k1, zero);
      f32x4 cC = MFMA_F16(aR2[0], b2k0, zero);
      cA = MFMA_F16(aI2[2], b1k2, cA);
      cB = MFMA_F16(aI2[3], b1k3, cB);
      cC = MFMA_F16(aR2[1], b2k1, cC);
      s = cA + cB + cC;
    };
    for (int t = 0; t < T; ++t) {
      const int cur = t & 1;
      if (t > 0) {
        const char* H1c = (const char*)smem + (cur ? H1_1 : H1_0);
        const char* H2r = (const char*)smem + (cur ? H2_0 : H2_1);
        char*       H2w = (char*)smem + (cur ? H2_1 : H2_0);
        f32x4 s;
        l2_body(H1c, H2r, s);
        uint32_t lo, hi;
        tanh_pack(s, lo, hi);
        *(uint2*)(H2w + woff2) = make_uint2(lo, hi);
      }
      sync_lds();
    }
    {
      f32x4 s;
      l2_body((const char*)smem + H1_0, (const char*)smem + H2_1, s);
      f32x4 hv;
#pragma unroll
      for (int r = 0; r < 4; ++r) hv[r] = tanh_fast(s[r]);
      *(f32x4*)(smem + H2F + n * 256 + (16 * j + 4 * g) * 4) = hv;
    }
  }
  sync_lds();
  if (tid < BB * 10) {
    const int b = tid / 10, c = tid % 10;
    const float* hrow = (const float*)(smem + H2F + b * 256);
    float acc = bfc[c];
#pragma unroll 8
    for (int k = 0; k < 64; ++k) acc += hrow[k] * Wfc[c * 64 + k];
    out[(size_t)(b0 + b) * 10 + c] = acc;
  }
}

extern "C" void kernel_launch(void* const* d_in, const int* in_sizes, int n_in,
                              void* d_out, int out_size, void* d_ws, size_t ws_size,
                              hipStream_t stream) {
  const float* x    = (const float*)d_in[0];
  const float* Wih1 = (const float*)d_in[1];
  const float* Whh1 = (const float*)d_in[2];
  const float* bih1 = (const float*)d_in[3];
  const float* bhh1 = (const float*)d_in[4];
  const float* Wih2 = (const float*)d_in[5];
  const float* Whh2 = (const float*)d_in[6];
  const float* bih2 = (const float*)d_in[7];
  const float* bhh2 = (const float*)d_in[8];
  const float* Wfc  = (const float*)d_in[9];
  const float* bfc  = (const float*)d_in[10];

  const size_t xw_bytes = (size_t)512 * 1024 * 128 * 2;  // 134 MB fp16
  if (ws_size >= xw_bytes) {
    uint2* xw = (uint2*)d_ws;
    hipLaunchKernelGGL(xw_pre, dim3(256), dim3(256), 0, stream,
                       x, Wih1, bih1, bhh1, xw);
    hipLaunchKernelGGL(rnn_rec, dim3(512 / 16), dim3(512), 0, stream,
                       Whh1, Wih2, Whh2, bih2, bhh2, Wfc, bfc,
                       (const uint2*)xw, (float*)d_out);
  } else {
    hipLaunchKernelGGL(rnn_fallback, dim3(512 / 16), dim3(512), 0, stream,
                       x, Wih1, Whh1, bih1, bhh1, Wih2, Whh2, bih2, bhh2,
                       Wfc, bfc, (float*)d_out);
  }
}

// Round 10
// 426.055 us; speedup vs baseline: 1.1634x; 1.1634x over previous
//
#include <hip/hip_runtime.h>
#include <stdint.h>

// ---------------------------------------------------------------------------
// Fused 2-layer tanh RNN + FC head for MI355X (gfx950).  Round 10.
//
// = r7's balanced wave split  +  r9's conflict-free lane-linear LDS layout.
//   (r9's A/B showed: layout fix good [conflicts 6.8M->1.6M], P-absorption
//    bad [+300cyc on the critical l1 wave].  This round keeps only the good.)
//
// KERNEL 1 xw_pre: xw[b][t] = Wih1 x[b][t] + b_ih1 + b_hh1 (fp16, MFMA C/D
//   fragment layout), 256 blocks, ~30us.
// KERNEL 2 rnn_rec: 32 blocks x 512 thr (8 waves), 16 batch rows/block.
//   Waves 0-3: layer-1 tiles {2w,2w+1} (8 MFMA, 8 tanh, 2 writes).
//   Waves 4-7: layer-2 tile w-4 (reads h1 panel + h2, 6 MFMA, 4 tanh),
//   lag-1 (step t: h2(t) from h1(t), h2(t-1)).  ONE lgkm-only barrier/step.
// LDS: lane-linear fragment layout [k-block(1KB)][lane*16]: ds_read_b128 at
//   base+lane*16 (canonical conflict-free); writes <=2-way (free).
// ---------------------------------------------------------------------------

typedef _Float16 f16x8 __attribute__((ext_vector_type(8)));
typedef _Float16 f16x4 __attribute__((ext_vector_type(4)));
typedef float f32x4 __attribute__((ext_vector_type(4)));

#define MFMA_F16(A, B, C) __builtin_amdgcn_mfma_f32_16x16x32_f16((A), (B), (C), 0, 0, 0)

__device__ __forceinline__ float tanh_fast(float x) {
  float t = __builtin_amdgcn_exp2f(x * 2.88539008177792681472f);
  return 1.0f - 2.0f * __builtin_amdgcn_rcpf(t + 1.0f);
}

__device__ __forceinline__ uint32_t pk16(float a, float b) {
  return __builtin_bit_cast(uint32_t, __builtin_amdgcn_cvt_pkrtz(a, b));
}

__device__ __forceinline__ void sync_lds() {
  asm volatile("s_waitcnt lgkmcnt(0)\n\ts_barrier" ::: "memory");
}

__device__ __forceinline__ f16x8 cvt8w(const float* s) {
  f32x4 a = *(const f32x4*)s;
  f32x4 b = *(const f32x4*)(s + 4);
  f16x8 r;
#pragma unroll
  for (int j = 0; j < 4; ++j) { r[j] = (_Float16)a[j]; r[4 + j] = (_Float16)b[j]; }
  return r;
}

__device__ __forceinline__ f16x8 pack_x8(const f32x4& a, const f32x4& b) {
  union { uint32_t u[4]; f16x8 v; } tmp;
  tmp.u[0] = pk16(a[0], a[1]); tmp.u[1] = pk16(a[2], a[3]);
  tmp.u[2] = pk16(b[0], b[1]); tmp.u[3] = pk16(b[2], b[3]);
  return tmp.v;
}

// ============================ kernel 1: xw precompute ========================
__global__ __launch_bounds__(256) void xw_pre(
    const float* __restrict__ x, const float* __restrict__ Wih1,
    const float* __restrict__ bih1, const float* __restrict__ bhh1,
    uint2* __restrict__ xw)
{
  const int tid  = threadIdx.x;
  const int w    = tid >> 6, lane = tid & 63;
  const int g    = lane >> 4, n = lane & 15;
  const int gb   = blockIdx.x >> 3;
  const int t0   = ((blockIdx.x & 7) << 7) + (w << 5);

  f16x8 aI[8];
  f32x4 bias[8];
#pragma unroll
  for (int m = 0; m < 8; ++m) {
    aI[m] = cvt8w(Wih1 + (m * 16 + n) * 32 + g * 8);
#pragma unroll
    for (int r = 0; r < 4; ++r)
      bias[m][r] = bih1[m * 16 + g * 4 + r] + bhh1[m * 16 + g * 4 + r];
  }

  const float* xp = x + ((size_t)(gb * 16 + n) * 1024 + t0) * 32 + g * 8;
  uint2* xo = xw + (size_t)(gb * 1024 + t0) * 512 + lane;

  f32x4 xa = *(const f32x4*)(xp);
  f32x4 xb = *(const f32x4*)(xp + 4);
  for (int tt = 0; tt < 32; ++tt) {
    f32x4 na, nb;
    if (tt < 31) {
      na = *(const f32x4*)(xp + (tt + 1) * 32);
      nb = *(const f32x4*)(xp + (tt + 1) * 32 + 4);
    }
    f16x8 xf = pack_x8(xa, xb);
#pragma unroll
    for (int m = 0; m < 8; ++m) {
      f32x4 d = MFMA_F16(aI[m], xf, bias[m]);
      xo[tt * 512 + m * 64] = make_uint2(pk16(d[0], d[1]), pk16(d[2], d[3]));
    }
    xa = na; xb = nb;
  }
}

// ============================ kernel 2: recurrence ===========================
__global__ __attribute__((amdgpu_waves_per_eu(2, 2))) __launch_bounds__(512)
void rnn_rec(
    const float* __restrict__ Whh1,
    const float* __restrict__ Wih2, const float* __restrict__ Whh2,
    const float* __restrict__ bih2, const float* __restrict__ bhh2,
    const float* __restrict__ Wfc,  const float* __restrict__ bfc,
    const uint2* __restrict__ xw,
    float* __restrict__ out)
{
  constexpr int T = 1024, H1 = 128, H2 = 64, BB = 16;
  // LDS map, lane-linear fragment layout [k-block(1KB)][lane*16]:
  constexpr int H1_0 = 0,    H1_1 = 4096;    // h1: 4 k-blocks x 1KB each buf
  constexpr int H2_0 = 8192, H2_1 = 10240;   // h2: 2 k-blocks x 1KB each buf
  constexpr int H2F  = 12288;                // final h2 f32: 16 rows x 256B
  __shared__ __align__(16) unsigned char smem[16384];

  const int tid  = threadIdx.x;
  const int w    = tid >> 6;      // wave 0..7
  const int lane = tid & 63;
  const int g    = lane >> 4;     // 0..3
  const int n    = lane & 15;     // batch col
  const int b0   = blockIdx.x * BB;

  // zero h1 buf0 (h1(0)=0) and h2 buf0 (h2(0)=0, read at t=1)
  {
    uint32_t* p = (uint32_t*)smem;
    for (int i = tid; i < 1024; i += 512) p[i] = 0u;   // H1_0
    uint32_t* q = (uint32_t*)(smem + H2_0);
    for (int i = tid; i < 512; i += 512) q[i] = 0u;    // H2_0
  }

  auto tanh_pack = [&](const f32x4& a, uint32_t& lo, uint32_t& hi) {
    lo = pk16(tanh_fast(a[0]), tanh_fast(a[1]));
    hi = pk16(tanh_fast(a[2]), tanh_fast(a[3]));
  };

  __syncthreads();

  const f32x4 zero = {0.f, 0.f, 0.f, 0.f};
  const int lb = lane * 16;  // lane-linear byte offset

  if (w < 4) {
    // ===== layer-1 wave: tiles {2w, 2w+1} = channels 32w..32w+31 =====
    f16x8 aU[2][4];
#pragma unroll
    for (int ti = 0; ti < 2; ++ti) {
      const int ch = (2 * w + ti) * 16 + n;
#pragma unroll
      for (int k4 = 0; k4 < 4; ++k4)
        aU[ti][k4] = cvt8w(Whh1 + ch * H1 + k4 * 32 + g * 8);
    }
    // write: ch = 32w+16ti+4g+r -> k-block w, sub-block 2ti+(g>>1),
    // byte n*16 + (g&1)*8 (+r*2 within the uint2)
    int woff[2];
#pragma unroll
    for (int ti = 0; ti < 2; ++ti)
      woff[ti] = w * 1024 + (2 * ti + (g >> 1)) * 256 + n * 16 + (g & 1) * 8;

    const uint2* xwp = xw + (size_t)blockIdx.x * T * 512 + lane;
    const int ti0 = (2 * w) * 64, ti1 = (2 * w + 1) * 64;

    auto cvtC = [](uint2 v) -> f32x4 {
      f16x4 h = __builtin_bit_cast(f16x4, v);
      f32x4 r;
#pragma unroll
      for (int i = 0; i < 4; ++i) r[i] = (float)h[i];
      return r;
    };

    uint2 qA0 = xwp[0 * 512 + ti0], qA1 = xwp[0 * 512 + ti1];
    uint2 qB0 = xwp[1 * 512 + ti0], qB1 = xwp[1 * 512 + ti1];

    auto stepL1 = [&](int t, int cur, uint2& s0, uint2& s1) {
      const char* H1c = (const char*)smem + (cur ? H1_1 : H1_0);
      char*       H1n = (char*)smem + (cur ? H1_0 : H1_1);
      f16x8 b1k0 = *(const f16x8*)(H1c + 0 * 1024 + lb);
      f16x8 b1k1 = *(const f16x8*)(H1c + 1 * 1024 + lb);
      f16x8 b1k2 = *(const f16x8*)(H1c + 2 * 1024 + lb);
      f16x8 b1k3 = *(const f16x8*)(H1c + 3 * 1024 + lb);
      f32x4 accI0 = cvtC(s0), accI1 = cvtC(s1);
      if (t + 2 < T) {  // prefetch xw(t+2) into the just-consumed slots
        s0 = xwp[(t + 2) * 512 + ti0];
        s1 = xwp[(t + 2) * 512 + ti1];
      }
      // two 2-deep chains per tile
      f32x4 aA0 = MFMA_F16(aU[0][0], b1k0, accI0);
      f32x4 aB0 = MFMA_F16(aU[0][2], b1k2, zero);
      f32x4 aA1 = MFMA_F16(aU[1][0], b1k0, accI1);
      f32x4 aB1 = MFMA_F16(aU[1][2], b1k2, zero);
      aA0 = MFMA_F16(aU[0][1], b1k1, aA0);
      aB0 = MFMA_F16(aU[0][3], b1k3, aB0);
      aA1 = MFMA_F16(aU[1][1], b1k1, aA1);
      aB1 = MFMA_F16(aU[1][3], b1k3, aB1);
      {
        f32x4 s0v = aA0 + aB0;
        uint32_t lo, hi;
        tanh_pack(s0v, lo, hi);
        *(uint2*)(H1n + woff[0]) = make_uint2(lo, hi);
      }
      {
        f32x4 s1v = aA1 + aB1;
        uint32_t lo, hi;
        tanh_pack(s1v, lo, hi);
        *(uint2*)(H1n + woff[1]) = make_uint2(lo, hi);
      }
      sync_lds();
    };

    for (int t = 0; t < T; t += 2) {
      stepL1(t + 0, 0, qA0, qA1);
      stepL1(t + 1, 1, qB0, qB1);
    }
  } else {
    // ===== layer-2 wave: tile j = w-4 (ch 16j..16j+15), lag-1 =====
    const int j = w - 4;
    f16x8 aI2[4], aR2[2];
#pragma unroll
    for (int k4 = 0; k4 < 4; ++k4)
      aI2[k4] = cvt8w(Wih2 + (16 * j + n) * H1 + k4 * 32 + g * 8);
#pragma unroll
    for (int k2 = 0; k2 < 2; ++k2)
      aR2[k2] = cvt8w(Whh2 + (16 * j + n) * H2 + k2 * 32 + g * 8);
    f32x4 bias2;
#pragma unroll
    for (int r = 0; r < 4; ++r)
      bias2[r] = bih2[16 * j + g * 4 + r] + bhh2[16 * j + g * 4 + r];

    // h2 write: ch = 16j+4g+r -> k-block j>>1, sub-block 2(j&1)+(g>>1)
    const int h2w = (j >> 1) * 1024 + (2 * (j & 1) + (g >> 1)) * 256
                  + n * 16 + (g & 1) * 8;

    auto l2_body = [&](const char* H1c, const char* H2r, f32x4& s) {
      f16x8 b1k0 = *(const f16x8*)(H1c + 0 * 1024 + lb);
      f16x8 b1k1 = *(const f16x8*)(H1c + 1 * 1024 + lb);
      f16x8 b1k2 = *(const f16x8*)(H1c + 2 * 1024 + lb);
      f16x8 b1k3 = *(const f16x8*)(H1c + 3 * 1024 + lb);
      f16x8 b2k0 = *(const f16x8*)(H2r + 0 * 1024 + lb);
      f16x8 b2k1 = *(const f16x8*)(H2r + 1 * 1024 + lb);
      f32x4 cA = MFMA_F16(aI2[0], b1k0, bias2);
      f32x4 cB = MFMA_F16(aI2[1], b1k1, zero);
      f32x4 cC = MFMA_F16(aR2[0], b2k0, zero);
      cA = MFMA_F16(aI2[2], b1k2, cA);
      cB = MFMA_F16(aI2[3], b1k3, cB);
      cC = MFMA_F16(aR2[1], b2k1, cC);
      s = cA + cB + cC;
    };

    // step t (t>=1): h2(t) = tanh(Wih2 h1(t) + Whh2 h2(t-1))
    //   reads h1 [H1 buf cur], h2 [H2 buf cur^1]; writes h2 [H2 buf cur].
    auto stepL2 = [&](int t, int cur) {
      if (t > 0) {
        const char* H1c = (const char*)smem + (cur ? H1_1 : H1_0);
        const char* H2r = (const char*)smem + (cur ? H2_0 : H2_1);
        char*       H2w = (char*)smem + (cur ? H2_1 : H2_0);
        f32x4 s;
        l2_body(H1c, H2r, s);
        uint32_t lo, hi;
        tanh_pack(s, lo, hi);
        *(uint2*)(H2w + h2w) = make_uint2(lo, hi);
      }
      sync_lds();
    };

    for (int t = 0; t < T; t += 2) {
      stepL2(t + 0, 0);
      stepL2(t + 1, 1);
    }

    // final: h2_ref(1023) from h1(1024) [H1_0] and h2(1023) [H2_1] -> H2F f32
    {
      f32x4 s;
      l2_body((const char*)smem + H1_0, (const char*)smem + H2_1, s);
      f32x4 hv;
#pragma unroll
      for (int r = 0; r < 4; ++r) hv[r] = tanh_fast(s[r]);
      *(f32x4*)(smem + H2F + n * 256 + (16 * j + 4 * g) * 4) = hv;
    }
  }

  sync_lds();  // join: h2f visible to all

  // ---- FC head: logits[b][c] = b_fc[c] + sum_k h2f[b][k] * Wfc[c][k] ----
  if (tid < BB * 10) {
    const int b = tid / 10, c = tid % 10;
    const float* hrow = (const float*)(smem + H2F + b * 256);
    float acc = bfc[c];
#pragma unroll 8
    for (int k = 0; k < 64; ++k) acc += hrow[k] * Wfc[c * 64 + k];
    out[(size_t)(b0 + b) * 10 + c] = acc;
  }
}

// ============================ fallback (no ws): r4-style =====================
__global__ __launch_bounds__(512) void rnn_fallback(
    const float* __restrict__ x,
    const float* __restrict__ Wih1, const float* __restrict__ Whh1,
    const float* __restrict__ bih1, const float* __restrict__ bhh1,
    const float* __restrict__ Wih2, const float* __restrict__ Whh2,
    const float* __restrict__ bih2, const float* __restrict__ bhh2,
    const float* __restrict__ Wfc,  const float* __restrict__ bfc,
    float* __restrict__ out)
{
  constexpr int T = 1024, I = 32, H1 = 128, H2 = 64, BB = 16;
  constexpr int R1 = 272, R2 = 144;
  constexpr int H1_0 = 0, H1_1 = 4352;
  constexpr int H2_0 = 8704, H2_1 = 11008;
  constexpr int H2F  = 13312;
  __shared__ __align__(16) unsigned char smem[17408];
  const int tid = threadIdx.x, w = tid >> 6, lane = tid & 63;
  const int g = lane >> 4, n = lane & 15, b0 = blockIdx.x * BB;
  {
    uint32_t* p = (uint32_t*)smem;
    for (int i = tid; i < 1088; i += 512) p[i] = 0u;
    uint32_t* q = (uint32_t*)(smem + H2_0);
    for (int i = tid; i < 576; i += 512) q[i] = 0u;
  }
  int roff1[4];
#pragma unroll
  for (int k4 = 0; k4 < 4; ++k4) roff1[k4] = n * R1 + k4 * 64 + g * 16;
  auto tanh_pack = [&](const f32x4& a, uint32_t& lo, uint32_t& hi) {
    lo = pk16(tanh_fast(a[0]), tanh_fast(a[1]));
    hi = pk16(tanh_fast(a[2]), tanh_fast(a[3]));
  };
  __syncthreads();
  const f32x4 zero = {0.f, 0.f, 0.f, 0.f};
  if (w < 4) {
    f16x8 aU[2][4], aI1[2];
    f32x4 bias1[2];
#pragma unroll
    for (int ti = 0; ti < 2; ++ti) {
      const int ch = (2 * w + ti) * 16 + n;
#pragma unroll
      for (int k4 = 0; k4 < 4; ++k4)
        aU[ti][k4] = cvt8w(Whh1 + ch * H1 + k4 * 32 + g * 8);
      aI1[ti] = cvt8w(Wih1 + ch * I + g * 8);
      const int cb = (2 * w + ti) * 16 + g * 4;
#pragma unroll
      for (int r = 0; r < 4; ++r) bias1[ti][r] = bih1[cb + r] + bhh1[cb + r];
    }
    int woff[2];
#pragma unroll
    for (int ti = 0; ti < 2; ++ti)
      woff[ti] = n * R1 + (2 * w + ti) * 32 + g * 8;
    const float* xp = x + (size_t)(b0 + n) * T * I + g * 8;
    f32x4 qa = *(const f32x4*)(xp), qb = *(const f32x4*)(xp + 4);
    f32x4 accI0, accI1;
    {
      f16x8 xf = pack_x8(qa, qb);
      accI0 = MFMA_F16(aI1[0], xf, bias1[0]);
      accI1 = MFMA_F16(aI1[1], xf, bias1[1]);
    }
    for (int t = 0; t < T; ++t) {
      const int cur = t & 1;
      const char* H1c = (const char*)smem + (cur ? H1_1 : H1_0);
      char*       H1n = (char*)smem + (cur ? H1_0 : H1_1);
      f16x8 b1k0 = *(const f16x8*)(H1c + roff1[0]);
      f16x8 b1k1 = *(const f16x8*)(H1c + roff1[1]);
      f16x8 b1k2 = *(const f16x8*)(H1c + roff1[2]);
      f16x8 b1k3 = *(const f16x8*)(H1c + roff1[3]);
      if (t + 1 < T) {
        qa = *(const f32x4*)(xp + (t + 1) * I);
        qb = *(const f32x4*)(xp + (t + 1) * I + 4);
      }
      f32x4 aA0 = MFMA_F16(aU[0][0], b1k0, accI0);
      f32x4 aB0 = MFMA_F16(aU[0][2], b1k2, zero);
      f32x4 aA1 = MFMA_F16(aU[1][0], b1k0, accI1);
      f32x4 aB1 = MFMA_F16(aU[1][2], b1k2, zero);
      aA0 = MFMA_F16(aU[0][1], b1k1, aA0);
      aB0 = MFMA_F16(aU[0][3], b1k3, aB0);
      aA1 = MFMA_F16(aU[1][1], b1k1, aA1);
      aB1 = MFMA_F16(aU[1][3], b1k3, aB1);
      if (t + 1 < T) {
        f16x8 xf = pack_x8(qa, qb);
        accI0 = MFMA_F16(aI1[0], xf, bias1[0]);
        accI1 = MFMA_F16(aI1[1], xf, bias1[1]);
      }
      uint32_t lo, hi;
      f32x4 s0 = aA0 + aB0;
      tanh_pack(s0, lo, hi);
      *(uint2*)(H1n + woff[0]) = make_uint2(lo, hi);
      f32x4 s1 = aA1 + aB1;
      tanh_pack(s1, lo, hi);
      *(uint2*)(H1n + woff[1]) = make_uint2(lo, hi);
      sync_lds();
    }
  } else {
    const int j = w - 4;
    f16x8 aI2[4], aR2[2];
#pragma unroll
    for (int k4 = 0; k4 < 4; ++k4)
      aI2[k4] = cvt8w(Wih2 + (16 * j + n) * H1 + k4 * 32 + g * 8);
#pragma unroll
    for (int k2 = 0; k2 < 2; ++k2)
      aR2[k2] = cvt8w(Whh2 + (16 * j + n) * H2 + k2 * 32 + g * 8);
    f32x4 bias2;
#pragma unroll
    for (int r = 0; r < 4; ++r)
      bias2[r] = bih2[16 * j + g * 4 + r] + bhh2[16 * j + g * 4 + r];
    int roff2[2];
#pragma unroll
    for (int k2 = 0; k2 < 2; ++k2) roff2[k2] = n * R2 + k2 * 64 + g * 16;
    const int woff2 = n * R2 + j * 32 + g * 8;
    auto l2_body = [&](const char* H1c, const char* H2r, f32x4& s) {
      f16x8 b1k0 = *(const f16x8*)(H1c + roff1[0]);
      f16x8 b1k1 = *(const f16x8*)(H1c + roff1[1]);
      f16x8 b1k2 = *(const f16x8*)(H1c + roff1[2]);
      f16x8 b1k3 = *(const f16x8*)(H1c + roff1[3]);
      f16x8 b2k0 = *(const f16x8*)(H2r + roff2[0]);
      f16x8 b2k1 = *(const f16x8*)(H2r + roff2[1]);
      f32x4 cA = MFMA_F16(aI2[0], b1k0, bias2);
      f32x4 cB = MFMA_F16(aI2[1], b1k1, zero);
      f32x4 cC = MFMA_F16(aR2[0], b2k0, zero);
      cA = MFMA_F16(aI2[2], b1k2, cA);
      cB = MFMA_F16(aI2[3], b1k3, cB);
      cC = MFMA_F16(aR2[1], b2k1, cC);
      s = cA + cB + cC;
    };
    for (int t = 0; t < T; ++t) {
      const int cur = t & 1;
      if (t > 0) {
        const char* H1c = (const char*)smem + (cur ? H1_1 : H1_0);
        const char* H2r = (const char*)smem + (cur ? H2_0 : H2_1);
        char*       H2w = (char*)smem + (cur ? H2_1 : H2_0);
        f32x4 s;
        l2_body(H1c, H2r, s);
        uint32_t lo, hi;
        tanh_pack(s, lo, hi);
        *(uint2*)(H2w + woff2) = make_uint2(lo, hi);
      }
      sync_lds();
    }
    {
      f32x4 s;
      l2_body((const char*)smem + H1_0, (const char*)smem + H2_1, s);
      f32x4 hv;
#pragma unroll
      for (int r = 0; r < 4; ++r) hv[r] = tanh_fast(s[r]);
      *(f32x4*)(smem + H2F + n * 256 + (16 * j + 4 * g) * 4) = hv;
    }
  }
  sync_lds();
  if (tid < BB * 10) {
    const int b = tid / 10, c = tid % 10;
    const float* hrow = (const float*)(smem + H2F + b * 256);
    float acc = bfc[c];
#pragma unroll 8
    for (int k = 0; k < 64; ++k) acc += hrow[k] * Wfc[c * 64 + k];
    out[(size_t)(b0 + b) * 10 + c] = acc;
  }
}

extern "C" void kernel_launch(void* const* d_in, const int* in_sizes, int n_in,
                              void* d_out, int out_size, void* d_ws, size_t ws_size,
                              hipStream_t stream) {
  const float* x    = (const float*)d_in[0];
  const float* Wih1 = (const float*)d_in[1];
  const float* Whh1 = (const float*)d_in[2];
  const float* bih1 = (const float*)d_in[3];
  const float* bhh1 = (const float*)d_in[4];
  const float* Wih2 = (const float*)d_in[5];
  const float* Whh2 = (const float*)d_in[6];
  const float* bih2 = (const float*)d_in[7];
  const float* bhh2 = (const float*)d_in[8];
  const float* Wfc  = (const float*)d_in[9];
  const float* bfc  = (const float*)d_in[10];

  const size_t xw_bytes = (size_t)512 * 1024 * 128 * 2;  // 134 MB fp16
  if (ws_size >= xw_bytes) {
    uint2* xw = (uint2*)d_ws;
    hipLaunchKernelGGL(xw_pre, dim3(256), dim3(256), 0, stream,
                       x, Wih1, bih1, bhh1, xw);
    hipLaunchKernelGGL(rnn_rec, dim3(512 / 16), dim3(512), 0, stream,
                       Whh1, Wih2, Whh2, bih2, bhh2, Wfc, bfc,
                       (const uint2*)xw, (float*)d_out);
  } else {
    hipLaunchKernelGGL(rnn_fallback, dim3(512 / 16), dim3(512), 0, stream,
                       x, Wih1, Whh1, bih1, bhh1, Wih2, Whh2, bih2, bhh2,
                       Wfc, bfc, (float*)d_out);
  }
}